// Round 11
// baseline (95.588 us; speedup 1.0000x reference)
//
#include <hip/hip_runtime.h>
#include <hip/hip_fp16.h>

// ---------------- problem constants ----------------
#define NIMG 32
#define CH   3
#define HIN  256
#define WIN  256
#define MARG 38          // 2*HZ_PAD + 32
#define HP   332         // HIN + 2*MARG
#define WP   332
#define HU   664         // 2*HP
#define WU   664
#define HO   256
#define WO   256

// plain fp16 upsampled intermediate, padded row pitch (cols 664..671 are zeros)
#define UPITCH  672
#define CHELEMS (664 * 672)

// LDS staging window for the warp (per 32x32 output tile)
#define PH 132            // max rows
#define PW 152            // max cols (19 x 8-elem slots), 8-aligned base
#define PWB (PW * 2)      // row pitch in bytes (304)

typedef __fp16 h2 __attribute__((ext_vector_type(2)));
typedef float  f2 __attribute__((ext_vector_type(2)));

// reflect (edge-excluding) for original 256-range, valid for r in [-255, 510]
__device__ __forceinline__ int refl(int r) {
    r = (r < 0) ? -r : r;
    return (r > 255) ? (510 - r) : r;
}

__device__ __forceinline__ unsigned hbits(float a, float b) {
    __half2 h = __floats2half2_rn(a, b);
    return *(unsigned*)&h;
}

// ---------------- KA: fused reflect-pad + 2x upsample -> plain fp16 (padded pitch) ----------------
// Stage-1: interior fast path (block-uniform, 40% of blocks). Stage-2: row-pair packed
// f32. Stage-3: single pass, adjacent row-pairs m=2mg,2mg+1 share 6 of 8 rows ->
// 8 ds_read_b128 per thread (was 14 over 2 passes); 4 x 8B stores at consecutive rows.
__global__ void __launch_bounds__(256) k_up2(const float* __restrict__ img,
                                             const float* __restrict__ hz,
                                             __fp16* __restrict__ ups, int ch0) {
    __shared__ float s_in[38][40];    // 38 rows x 39 cols used
    __shared__ float s_mid[38][68];   // cols 0..65 used
    int ch  = blockIdx.z;
    int ty0 = blockIdx.y * 64;
    int tx0 = blockIdx.x * 64;
    int jy0 = (ty0 >> 1) - 3;
    int jx0 = (tx0 >> 1) - 3;
    int tid = threadIdx.x;
    float fs[12];                     // 2*f[i] (exact scaling)
#pragma unroll
    for (int i = 0; i < 12; ++i) fs[i] = 2.0f * hz[i];
    const float* base = img + (size_t)(ch0 + ch) * HIN * WIN;

    // stage 1: padded input patch (38 x 39), zero outside [0,332)^2
    if (jy0 >= 38 && jy0 <= 256 && jx0 >= 38 && jx0 <= 255) {
        // interior: patch maps 1:1 to input, no reflect/bounds (block-uniform branch)
        const float* bsrc = base + (jy0 - MARG) * WIN + (jx0 - MARG);
        for (int i = tid; i < 38 * 39; i += 256) {
            int ly = i / 39, lx = i - ly * 39;
            s_in[ly][lx] = bsrc[ly * WIN + lx];
        }
    } else {
        for (int i = tid; i < 38 * 39; i += 256) {
            int ly = i / 39, lx = i - ly * 39;
            int gy = jy0 + ly, gx = jx0 + lx;
            float v = 0.0f;
            if (gy >= 0 && gy < HP && gx >= 0 && gx < WP)
                v = base[refl(gy - MARG) * WIN + refl(gx - MARG)];
            s_in[ly][lx] = v;
        }
    }
    __syncthreads();

    // stage 2: horizontal upsample, row-pairs packed: item = (ly pair, j), 19x33
    for (int i = tid; i < 19 * 33; i += 256) {
        int j = i % 33, lp = i / 33;
        int ly = 2 * lp;
        const float* ra = &s_in[ly][j];
        const float* rb = &s_in[ly + 1][j];
        f2 ev = {0.0f, 0.0f}, od = {0.0f, 0.0f};   // .x = row ly, .y = row ly+1
#pragma unroll
        for (int t = 0; t < 6; ++t) {
            f2 ta; ta.x = ra[t];     ta.y = rb[t];       // ds_read2_b32 (offsets 40 apart)
            f2 tb; tb.x = ra[t + 1]; tb.y = rb[t + 1];
            ev += fs[11 - 2 * t] * ta;
            od += fs[10 - 2 * t] * tb;
        }
        f2 lo; lo.x = ev.x; lo.y = od.x;
        f2 hi; hi.x = ev.y; hi.y = od.y;
        *(f2*)&s_mid[ly][2 * j]     = lo;
        *(f2*)&s_mid[ly + 1][2 * j] = hi;
    }
    __syncthreads();

    // stage 3: vertical upsample, single pass; thread (qx, mg) does row-pairs
    // m = 2mg and 2mg+1 -> rows 2mg..2mg+7 loaded once; outputs gy0..gy0+3.
    // gy0 = ty0 + 4*mg is 0 mod 4 and HU is 0 mod 4 -> whole group in or out.
    {
        int qx = tid & 15;
        int mg = tid >> 4;            // 0..15
        int m0 = 2 * mg;
        int gx0 = tx0 + 4 * qx;
        int gy0 = ty0 + 4 * mg;
        __fp16* upch = ups + (size_t)ch * CHELEMS;
        if (gy0 < HU) {
            if (gx0 + 3 < WU) {
                float4 r0 = *(const float4*)&s_mid[m0 + 0][4 * qx];
                float4 r1 = *(const float4*)&s_mid[m0 + 1][4 * qx];
                float4 r2 = *(const float4*)&s_mid[m0 + 2][4 * qx];
                float4 r3 = *(const float4*)&s_mid[m0 + 3][4 * qx];
                float4 r4 = *(const float4*)&s_mid[m0 + 4][4 * qx];
                float4 r5 = *(const float4*)&s_mid[m0 + 5][4 * qx];
                float4 r6 = *(const float4*)&s_mid[m0 + 6][4 * qx];
                float4 r7 = *(const float4*)&s_mid[m0 + 7][4 * qx];
                f2 a0; a0.x = r0.x; a0.y = r0.y;  f2 b0; b0.x = r0.z; b0.y = r0.w;
                f2 a1; a1.x = r1.x; a1.y = r1.y;  f2 b1; b1.x = r1.z; b1.y = r1.w;
                f2 a2; a2.x = r2.x; a2.y = r2.y;  f2 b2; b2.x = r2.z; b2.y = r2.w;
                f2 a3; a3.x = r3.x; a3.y = r3.y;  f2 b3; b3.x = r3.z; b3.y = r3.w;
                f2 a4; a4.x = r4.x; a4.y = r4.y;  f2 b4; b4.x = r4.z; b4.y = r4.w;
                f2 a5; a5.x = r5.x; a5.y = r5.y;  f2 b5; b5.x = r5.z; b5.y = r5.w;
                f2 a6; a6.x = r6.x; a6.y = r6.y;  f2 b6; b6.x = r6.z; b6.y = r6.w;
                f2 a7; a7.x = r7.x; a7.y = r7.y;  f2 b7; b7.x = r7.z; b7.y = r7.w;
                // m = 2mg: even -> row gy0, odd -> gy0+1
                f2 eA01 = fs[11]*a0 + fs[9]*a1 + fs[7]*a2 + fs[5]*a3 + fs[3]*a4 + fs[1]*a5;
                f2 eA23 = fs[11]*b0 + fs[9]*b1 + fs[7]*b2 + fs[5]*b3 + fs[3]*b4 + fs[1]*b5;
                f2 oA01 = fs[10]*a1 + fs[8]*a2 + fs[6]*a3 + fs[4]*a4 + fs[2]*a5 + fs[0]*a6;
                f2 oA23 = fs[10]*b1 + fs[8]*b2 + fs[6]*b3 + fs[4]*b4 + fs[2]*b5 + fs[0]*b6;
                // m = 2mg+1: even -> row gy0+2, odd -> gy0+3
                f2 eB01 = fs[11]*a1 + fs[9]*a2 + fs[7]*a3 + fs[5]*a4 + fs[3]*a5 + fs[1]*a6;
                f2 eB23 = fs[11]*b1 + fs[9]*b2 + fs[7]*b3 + fs[5]*b4 + fs[3]*b5 + fs[1]*b6;
                f2 oB01 = fs[10]*a2 + fs[8]*a3 + fs[6]*a4 + fs[4]*a5 + fs[2]*a6 + fs[0]*a7;
                f2 oB23 = fs[10]*b2 + fs[8]*b3 + fs[6]*b4 + fs[4]*b5 + fs[2]*b6 + fs[0]*b7;
                uint2 q0, q1, q2, q3;
                q0.x = hbits(eA01.x, eA01.y); q0.y = hbits(eA23.x, eA23.y);
                q1.x = hbits(oA01.x, oA01.y); q1.y = hbits(oA23.x, oA23.y);
                q2.x = hbits(eB01.x, eB01.y); q2.y = hbits(eB23.x, eB23.y);
                q3.x = hbits(oB01.x, oB01.y); q3.y = hbits(oB23.x, oB23.y);
                *(uint2*)&upch[(size_t)(gy0 + 0) * UPITCH + gx0] = q0;
                *(uint2*)&upch[(size_t)(gy0 + 1) * UPITCH + gx0] = q1;
                *(uint2*)&upch[(size_t)(gy0 + 2) * UPITCH + gx0] = q2;
                *(uint2*)&upch[(size_t)(gy0 + 3) * UPITCH + gx0] = q3;
            } else if (gx0 >= WU && gx0 < UPITCH) {
                uint2 z; z.x = 0u; z.y = 0u;   // zero pad cols 664..671
                *(uint2*)&upch[(size_t)(gy0 + 0) * UPITCH + gx0] = z;
                *(uint2*)&upch[(size_t)(gy0 + 1) * UPITCH + gx0] = z;
                *(uint2*)&upch[(size_t)(gy0 + 2) * UPITCH + gx0] = z;
                *(uint2*)&upch[(size_t)(gy0 + 3) * UPITCH + gx0] = z;
            }
        }
    }
}

// ---------------- gather helpers ----------------
// act-free: out-of-tile samples (lwy/lwx in [74,80)) write into s_wh's padding
// (max waddr 79*82+79 = 6557 < 6560), which ph2 never reads (rows<74, cols<=73).
struct GS {
    int a_rd;        // clamped LDS byte addr of (ly, e) halfword pair
    unsigned sh;     // alignbit shift (0 or 16)
    int waddr;       // s_wh element index
    float wyf;       // y lerp weight
    h2 wv;           // packed (1-wx, wx)
};

__device__ __forceinline__ GS gmake(float rx, float ry, int wadd) {
    GS g;
    int lx = (int)rx;                               // trunc == floor (rx>=0 when in-tile)
    int ly = (int)ry;
    float wx = __builtin_amdgcn_fractf(rx);         // == rx - floor(rx); exact, 1 instr
    g.wyf    = __builtin_amdgcn_fractf(ry);
    unsigned a = (unsigned)(ly * PWB + (lx & ~1) * 2);
    const unsigned amax = (PH - 1) * PWB - 8;
    g.a_rd = (int)(a > amax ? amax : a);            // single v_min_u32: negatives wrap huge
    g.sh = ((unsigned)lx & 1u) << 4;
    g.waddr = wadd;
    g.wv = __builtin_amdgcn_cvt_pkrtz(1.0f - wx, wx);
    return g;
}

__device__ __forceinline__ void gfinish(const GS& g, unsigned w0, unsigned w1,
                                        unsigned w2, unsigned w3, __fp16* s_wh) {
    unsigned u0 = __builtin_amdgcn_alignbit(w1, w0, g.sh);
    unsigned u1 = __builtin_amdgcn_alignbit(w3, w2, g.sh);
    h2 h0; *(unsigned*)&h0 = u0;
    h2 h1; *(unsigned*)&h1 = u1;
    float r0 = __builtin_amdgcn_fdot2(h0, g.wv, 0.0f, false);
    float r1 = __builtin_amdgcn_fdot2(h1, g.wv, 0.0f, false);
    s_wh[g.waddr] = (__fp16)(r0 + g.wyf * (r1 - r0));   // unconditional
}

// ---------------- KB: LDS-staged bilinear warp + 2x downsample (512 threads) ----------------
// Per-image affine coefs computed inline (exact k_setup arithmetic, wave-uniform)
// -> the separate 1-block k_setup dispatch and its launch gap are gone.
__global__ void __launch_bounds__(512) k_warpdn(const __fp16* __restrict__ ups,
                                                const float* __restrict__ th,
                                                const float* __restrict__ ls,
                                                const float* __restrict__ txp,
                                                const float* __restrict__ typ,
                                                const float* __restrict__ hz,
                                                float* __restrict__ out,
                                                int n0, int ch0) {
    __shared__ __align__(16) unsigned char s_raw[PH * PWB];      // 40.1 KB
    __shared__ __fp16 s_wh[80 * 82];                             // 13.1 KB
    __fp16* s_src = (__fp16*)s_raw;
    h2*     s_m2  = (h2*)s_raw;      // aliases s_src (disjoint live ranges)

    int ch  = blockIdx.z;
    int ty0 = blockIdx.y * 32;
    int tx0 = blockIdx.x * 32;
    int tid = threadIdx.x;

    // ---- inline per-image coefficients (bit-identical to the old k_setup) ----
    int n = n0 + ch / CH;
    float cth = cosf(th[n]);
    float sth = sinf(th[n]);
    float inv_s = 1.0f / expf(ls[n]);
    float tX = -txp[n] * (float)WIN;
    float tY = -typ[n] * (float)HIN;
    float A00 = inv_s * cth,  A01 = inv_s * sth, A02 = inv_s * (cth * tX + sth * tY);
    float A10 = -inv_s * sth, A11 = inv_s * cth, A12 = inv_s * (-sth * tX + cth * tY);
    A02 *= 2.0f; A12 *= 2.0f;
    A02 += 0.5f * (A00 + A01) - 0.5f;
    A12 += 0.5f * (A10 + A11) - 0.5f;
    const float Wu = (float)HU, Hu = (float)HU;
    const float Wt = 524.0f, Ht = 524.0f;
    float B00 = A00 * (2.0f / Wu) * (Wt * 0.5f);
    float B01 = A01 * (2.0f / Wu) * (Ht * 0.5f);
    float B02 = A02 * (2.0f / Wu);
    float B10 = A10 * (2.0f / Hu) * (Wt * 0.5f);
    float B11 = A11 * (2.0f / Hu) * (Ht * 0.5f);
    float B12 = A12 * (2.0f / Hu);
    float cxx = B00 * Wu / Wt;
    float cxy = B01 * Wu / Ht;
    float cx0 = 0.5f * ((B00 * (1.0f / Wt - 1.0f) + B01 * (1.0f / Ht - 1.0f) + B02 + 1.0f) * Wu - 1.0f);
    float cyx = B10 * Hu / Wt;
    float cyy = B11 * Hu / Ht;
    float cy0 = 0.5f * ((B10 * (1.0f / Wt - 1.0f) + B11 * (1.0f / Ht - 1.0f) + B12 + 1.0f) * Hu - 1.0f);

    const __fp16* upc = ups + (size_t)ch * CHELEMS;
    const unsigned short* us = (const unsigned short*)upc;
    int wy0 = 2 * ty0 + 1, wx0 = 2 * tx0 + 1;
    float wx0f = (float)wx0, wy0f = (float)wy0;

    // source bbox from tile corners (affine -> corners bound everything)
    float ix00 = cxx * wx0f + cxy * wy0f + cx0;
    float iy00 = cyx * wx0f + cyy * wy0f + cy0;
    float dxx = cxx * 73.0f, dxy = cxy * 73.0f;
    float dyx = cyx * 73.0f, dyy = cyy * 73.0f;
    float ixmin = ix00 + fminf(dxx, 0.0f) + fminf(dxy, 0.0f);
    float ixmax = ix00 + fmaxf(dxx, 0.0f) + fmaxf(dxy, 0.0f);
    float iymin = iy00 + fminf(dyx, 0.0f) + fminf(dyy, 0.0f);
    float iymax = iy00 + fmaxf(dyx, 0.0f) + fmaxf(dyy, 0.0f);
    int x_lo = (int)floorf(ixmin) - 1;
    int x_base = x_lo & ~7;
    int x_hi = (int)floorf(ixmax) + 2;
    int y_lo = (int)floorf(iymin) - 1;
    int y_hi = (int)floorf(iymax) + 2;
    int Rn = y_hi - y_lo + 1;
    int Wn = x_hi - x_base + 1;
    bool ldsok = (Rn <= PH) && (Wn <= PW);

    int wave = __builtin_amdgcn_readfirstlane(tid >> 6);   // 0..7
    int lane = tid & 63;
    int ply = lane >> 3, plx = lane & 7;
    float ix_l = cxx * (float)(wx0 + plx) + cxy * (float)(wy0 + ply) + cx0;
    float iy_l = cyx * (float)(wx0 + plx) + cyy * (float)(wy0 + ply) + cy0;
    float c8xx = 8.0f * cxx, c8xy = 8.0f * cxy;
    float c8yx = 8.0f * cyx, c8yy = 8.0f * cyy;

    if (ldsok) {
        // ---- stage bbox into LDS, dense per-lane (row,slot) mapping ----
        int spr = (Wn + 7) >> 3;                  // slots per row, <= 19
        int rpp = 64 / spr;                       // rows per wave-pass
        float rcp = 1.0f / (float)spr;
        int lrow = (int)((float)lane * rcp);
        if (lrow * spr > lane) lrow--;
        if ((lrow + 1) * spr <= lane) lrow++;
        int lslot = lane - lrow * spr;
        // interior: every staged 16B chunk is in-bounds (block-uniform branch)
        bool sint = (y_lo >= 0) && (y_lo + Rn <= HU) &&
                    (x_base >= 0) && (x_base + spr * 8 <= UPITCH);
        if (lrow < rpp) {
            int gx = x_base + lslot * 8;
            if (sint) {
                const unsigned char* src = (const unsigned char*)
                    &upc[(size_t)(y_lo + wave * rpp + lrow) * UPITCH + gx];
                for (int row = wave * rpp + lrow; row < Rn; row += 8 * rpp) {
                    *(uint4*)&s_src[row * PW + lslot * 8] = *(const uint4*)src;
                    src += (size_t)(8 * rpp) * UPITCH * sizeof(__fp16);
                }
            } else {
                for (int row = wave * rpp + lrow; row < Rn; row += 8 * rpp) {
                    int gy = y_lo + row;
                    uint4 val;
                    if (gy >= 0 && gy < HU && gx >= 0 && gx <= UPITCH - 8) {
                        val = *(const uint4*)&upc[(size_t)gy * UPITCH + gx];
                    } else if (gy >= 0 && gy < HU) {
                        unsigned part[4];
#pragma unroll
                        for (int k = 0; k < 4; ++k) {
                            int ga = gx + 2 * k, gb = ga + 1;
                            unsigned lo = (ga >= 0 && ga < WU) ? (unsigned)us[(size_t)gy * UPITCH + ga] : 0u;
                            unsigned hi = (gb >= 0 && gb < WU) ? (unsigned)us[(size_t)gy * UPITCH + gb] : 0u;
                            part[k] = lo | (hi << 16);
                        }
                        val.x = part[0]; val.y = part[1]; val.z = part[2]; val.w = part[3];
                    } else {
                        val.x = 0u; val.y = 0u; val.z = 0u; val.w = 0u;
                    }
                    *(uint4*)&s_src[row * PW + lslot * 8] = val;
                }
            }
        }
        __syncthreads();

        // ---- warp from LDS: depth-2 pipelined, column-major incremental stepping ----
        float ixb = ix_l - (float)x_base;
        float iyb = iy_l - (float)y_lo;
        int wbase = ply * 82 + plx;
        float rx = ixb + (float)wave * c8xy;          // px=0, py=wave
        float ry = iyb + (float)wave * c8yy;
        int wadd = wbase + wave * 656;
        int py = wave;
        const float sxA = 8.0f * c8xy,            syA = 8.0f * c8yy;
        const float sxB = c8xx - 2.0f * c8xy,     syB = c8yx - 2.0f * c8yy;
        int tc = (wave < 4) ? 13 : 12;            // idx = wave + 8k < 100

        GS g0 = gmake(rx, ry, wadd);
        {   int pyn = py + 8;
            if (pyn >= 10) { rx += sxB; ry += syB; wadd += 8 - 2 * 656; py = pyn - 10; }
            else           { rx += sxA; ry += syA; wadd += 8 * 656;     py = pyn; } }
        const unsigned* q0 = (const unsigned*)(s_raw + g0.a_rd);
        unsigned a0 = q0[0], a1 = q0[1], a2 = q0[PWB / 4], a3 = q0[PWB / 4 + 1];
        for (int k = 1; k < tc; ++k) {
            GS g1 = gmake(rx, ry, wadd);
            {   int pyn = py + 8;
                if (pyn >= 10) { rx += sxB; ry += syB; wadd += 8 - 2 * 656; py = pyn - 10; }
                else           { rx += sxA; ry += syA; wadd += 8 * 656;     py = pyn; } }
            const unsigned* q1 = (const unsigned*)(s_raw + g1.a_rd);
            unsigned b0 = q1[0], b1 = q1[1], b2 = q1[PWB / 4], b3 = q1[PWB / 4 + 1];
            gfinish(g0, a0, a1, a2, a3, s_wh);
            g0 = g1; a0 = b0; a1 = b1; a2 = b2; a3 = b3;
        }
        gfinish(g0, a0, a1, a2, a3, s_wh);
    } else {
        // ---- fallback: guarded global gather (rare: bbox too large) ----
        for (int pp = wave; pp < 100; pp += 8) {
            int py = (pp * 205) >> 11;
            int px = pp - py * 10;
            int lwy = py * 8 + ply;
            int lwx = px * 8 + plx;
            if (lwy < 74 && lwx < 74) {
                float ix = ix_l + (float)px * c8xx + (float)py * c8xy;
                float iy = iy_l + (float)px * c8yx + (float)py * c8yy;
                float fx = floorf(ix), fy = floorf(iy);
                float wx = ix - fx, wyf = iy - fy;
                int x0 = (int)fx, y0 = (int)fy;
                int xc0 = min(max(x0, 0), WU - 1);
                int xc1 = min(max(x0 + 1, 0), WU - 1);
                int yc0 = min(max(y0, 0), HU - 1);
                int yc1 = min(max(y0 + 1, 0), HU - 1);
                float mx0 = (x0 >= 0 && x0 < WU) ? 1.0f : 0.0f;
                float mx1 = (x0 >= -1 && x0 < WU - 1) ? 1.0f : 0.0f;
                float my0 = (y0 >= 0 && y0 < HU) ? 1.0f : 0.0f;
                float my1 = (y0 >= -1 && y0 < HU - 1) ? 1.0f : 0.0f;
                float t00 = (float)upc[(size_t)yc0 * UPITCH + xc0] * mx0;
                float t01 = (float)upc[(size_t)yc0 * UPITCH + xc1] * mx1;
                float t10 = (float)upc[(size_t)yc1 * UPITCH + xc0] * mx0;
                float t11 = (float)upc[(size_t)yc1 * UPITCH + xc1] * mx1;
                float r0 = t00 + wx * (t01 - t00);
                float r1 = t10 + wx * (t11 - t10);
                s_wh[lwy * 82 + lwx] = (__fp16)(r0 * (1.0f - wyf) * my0 + r1 * wyf * my1);
            }
        }
    }
    __syncthreads();

    // packed filter registers
    float f[12];
#pragma unroll
    for (int i = 0; i < 12; ++i) f[i] = hz[i];
    h2 Fe[6];
#pragma unroll
    for (int i = 0; i < 6; ++i) { Fe[i][0] = (__fp16)f[2 * i]; Fe[i][1] = (__fp16)f[2 * i + 1]; }

    // phase 2: horizontal downsample via fdot2 on fp16 pairs -> s_m2 (aliases s_src)
    for (int i = tid; i < 74 * 16; i += 512) {
        int j = i & 15, lwy = i >> 4;
        const __fp16* r = &s_wh[lwy * 82 + 4 * j];
        h2 P0 = *(const h2*)(r + 0);
        h2 P1 = *(const h2*)(r + 2);
        h2 P2 = *(const h2*)(r + 4);
        h2 P3 = *(const h2*)(r + 6);
        h2 P4 = *(const h2*)(r + 8);
        h2 P5 = *(const h2*)(r + 10);
        h2 P6 = *(const h2*)(r + 12);
        float ev = __builtin_amdgcn_fdot2(P0, Fe[0],
                   __builtin_amdgcn_fdot2(P1, Fe[1],
                   __builtin_amdgcn_fdot2(P2, Fe[2],
                   __builtin_amdgcn_fdot2(P3, Fe[3],
                   __builtin_amdgcn_fdot2(P4, Fe[4],
                   __builtin_amdgcn_fdot2(P5, Fe[5], 0.0f, false), false), false), false), false), false);
        float od = __builtin_amdgcn_fdot2(P1, Fe[0],
                   __builtin_amdgcn_fdot2(P2, Fe[1],
                   __builtin_amdgcn_fdot2(P3, Fe[2],
                   __builtin_amdgcn_fdot2(P4, Fe[3],
                   __builtin_amdgcn_fdot2(P5, Fe[4],
                   __builtin_amdgcn_fdot2(P6, Fe[5], 0.0f, false), false), false), false), false), false);
        h2 sm; sm[0] = (__fp16)ev; sm[1] = (__fp16)od;
        s_m2[lwy * 17 + j] = sm;
    }
    __syncthreads();

    // phase 3: vertical downsample via perm-paired fdot2
    {
        int j = tid & 15, my = tid >> 4;    // 512 threads == 32x16 exactly
        const unsigned* m2u = (const unsigned*)s_m2;
        float ev = 0.0f, od = 0.0f;
#pragma unroll
        for (int t = 0; t < 12; t += 2) {
            unsigned ha = m2u[(2 * my + t) * 17 + j];
            unsigned hb = m2u[(2 * my + t + 1) * 17 + j];
            unsigned pe = __builtin_amdgcn_perm(hb, ha, 0x05040100u);  // (ha.lo, hb.lo)
            unsigned po = __builtin_amdgcn_perm(hb, ha, 0x07060302u);  // (ha.hi, hb.hi)
            h2 he; *(unsigned*)&he = pe;
            h2 ho; *(unsigned*)&ho = po;
            ev = __builtin_amdgcn_fdot2(he, Fe[t >> 1], ev, false);
            od = __builtin_amdgcn_fdot2(ho, Fe[t >> 1], od, false);
        }
        float2 o; o.x = ev; o.y = od;
        *(float2*)&out[(size_t)(ch0 + ch) * HO * WO + (size_t)(ty0 + my) * WO + (tx0 + 2 * j)] = o;
    }
}

// ---------------- launch ----------------
extern "C" void kernel_launch(void* const* d_in, const int* in_sizes, int n_in,
                              void* d_out, int out_size, void* d_ws, size_t ws_size,
                              hipStream_t stream) {
    const float* images = (const float*)d_in[0];
    const float* theta  = (const float*)d_in[1];
    const float* log_s  = (const float*)d_in[2];
    const float* tx     = (const float*)d_in[3];
    const float* ty     = (const float*)d_in[4];
    const float* hz     = (const float*)d_in[5];
    float* out = (float*)d_out;

    // cn=32: single chunk (85.6 MB intermediate). Removes dispatch gaps; warpdn
    // 6144 blocks @ 3/CU = 8 full residency rounds (round-2 lesson: partial
    // rounds = 2x tail loss). k_setup fused into warpdn -> 2 dispatches total.
    int cn = 32;
    while (cn > 1) {
        size_t needed = (size_t)cn * CH * CHELEMS * sizeof(__fp16);
        if (needed <= ws_size) break;
        cn >>= 1;
    }
    __fp16* upsb = (__fp16*)d_ws;

    const int TA = (HU + 63) / 64;    // 11
    for (int n0 = 0; n0 < NIMG; n0 += cn) {
        int nch = cn * CH;
        int ch0 = n0 * CH;
        hipLaunchKernelGGL(k_up2, dim3(TA, TA, nch), dim3(256), 0, stream,
                           images, hz, upsb, ch0);
        hipLaunchKernelGGL(k_warpdn, dim3(WO / 32, HO / 32, nch), dim3(512), 0, stream,
                           upsb, theta, log_s, tx, ty, hz, out, n0, ch0);
    }
}

// Round 12
// 94.386 us; speedup vs baseline: 1.0127x; 1.0127x over previous
//
#include <hip/hip_runtime.h>
#include <hip/hip_fp16.h>

// ---------------- problem constants ----------------
#define NIMG 32
#define CH   3
#define HIN  256
#define WIN  256
#define MARG 38          // 2*HZ_PAD + 32
#define HP   332         // HIN + 2*MARG
#define WP   332
#define HU   664         // 2*HP
#define WU   664
#define HO   256
#define WO   256

// plain fp16 upsampled intermediate, padded row pitch (cols 664..671 are zeros)
#define UPITCH  672
#define CHELEMS (664 * 672)

// LDS staging window for the warp (per 32x32 output tile)
#define PH 132            // max rows
#define PW 152            // max cols (19 x 8-elem slots), 8-aligned base
#define PWB (PW * 2)      // row pitch in bytes (304)

typedef __fp16 h2 __attribute__((ext_vector_type(2)));
typedef float  f2 __attribute__((ext_vector_type(2)));

// reflect (edge-excluding) for original 256-range, valid for r in [-255, 510]
__device__ __forceinline__ int refl(int r) {
    r = (r < 0) ? -r : r;
    return (r > 255) ? (510 - r) : r;
}

// ---------------- per-image affine coefficients (ONCE per batch; round-11 lesson:
// inlining this into warpdn repeats transcendentals 6144x = +8 us) ----------------
__global__ void k_setup(const float* __restrict__ th, const float* __restrict__ ls,
                        const float* __restrict__ txp, const float* __restrict__ typ,
                        float* __restrict__ coef) {
    int n = blockIdx.x * blockDim.x + threadIdx.x;
    if (n >= NIMG) return;
    float c  = cosf(th[n]);
    float sn = sinf(th[n]);
    float inv_s = 1.0f / expf(ls[n]);
    float tX = -txp[n] * (float)WIN;
    float tY = -typ[n] * (float)HIN;
    float A00 = inv_s * c,    A01 = inv_s * sn,  A02 = inv_s * (c * tX + sn * tY);
    float A10 = -inv_s * sn,  A11 = inv_s * c,   A12 = inv_s * (-sn * tX + c * tY);
    A02 *= 2.0f; A12 *= 2.0f;
    A02 += 0.5f * (A00 + A01) - 0.5f;
    A12 += 0.5f * (A10 + A11) - 0.5f;
    const float Wu = (float)HU, Hu = (float)HU;
    const float Wt = 524.0f, Ht = 524.0f;
    float B00 = A00 * (2.0f / Wu) * (Wt * 0.5f);
    float B01 = A01 * (2.0f / Wu) * (Ht * 0.5f);
    float B02 = A02 * (2.0f / Wu);
    float B10 = A10 * (2.0f / Hu) * (Wt * 0.5f);
    float B11 = A11 * (2.0f / Hu) * (Ht * 0.5f);
    float B12 = A12 * (2.0f / Hu);
    float cxx = B00 * Wu / Wt;
    float cxy = B01 * Wu / Ht;
    float cx0 = 0.5f * ((B00 * (1.0f / Wt - 1.0f) + B01 * (1.0f / Ht - 1.0f) + B02 + 1.0f) * Wu - 1.0f);
    float cyx = B10 * Hu / Wt;
    float cyy = B11 * Hu / Ht;
    float cy0 = 0.5f * ((B10 * (1.0f / Wt - 1.0f) + B11 * (1.0f / Ht - 1.0f) + B12 + 1.0f) * Hu - 1.0f);
    coef[n * 6 + 0] = cxx;
    coef[n * 6 + 1] = cxy;
    coef[n * 6 + 2] = cx0;
    coef[n * 6 + 3] = cyx;
    coef[n * 6 + 4] = cyy;
    coef[n * 6 + 5] = cy0;
}

__device__ __forceinline__ unsigned hbits(float a, float b) {
    __half2 h = __floats2half2_rn(a, b);
    return *(unsigned*)&h;
}

// ---------------- KA: fused reflect-pad + 2x upsample -> plain fp16 (padded pitch) ----------------
// Stage-1: interior fast path (block-uniform, 40% of blocks). Stage-2: row-pair packed
// f32. Stage-3: single pass, adjacent row-pairs m=2mg,2mg+1 share 6 of 8 rows ->
// 8 ds_read_b128 per thread (was 14 over 2 passes); 4 x 8B stores at consecutive rows.
__global__ void __launch_bounds__(256) k_up2(const float* __restrict__ img,
                                             const float* __restrict__ hz,
                                             __fp16* __restrict__ ups, int ch0) {
    __shared__ float s_in[38][40];    // 38 rows x 39 cols used
    __shared__ float s_mid[38][68];   // cols 0..65 used
    int ch  = blockIdx.z;
    int ty0 = blockIdx.y * 64;
    int tx0 = blockIdx.x * 64;
    int jy0 = (ty0 >> 1) - 3;
    int jx0 = (tx0 >> 1) - 3;
    int tid = threadIdx.x;
    float fs[12];                     // 2*f[i] (exact scaling)
#pragma unroll
    for (int i = 0; i < 12; ++i) fs[i] = 2.0f * hz[i];
    const float* base = img + (size_t)(ch0 + ch) * HIN * WIN;

    // stage 1: padded input patch (38 x 39), zero outside [0,332)^2
    if (jy0 >= 38 && jy0 <= 256 && jx0 >= 38 && jx0 <= 255) {
        // interior: patch maps 1:1 to input, no reflect/bounds (block-uniform branch)
        const float* bsrc = base + (jy0 - MARG) * WIN + (jx0 - MARG);
        for (int i = tid; i < 38 * 39; i += 256) {
            int ly = i / 39, lx = i - ly * 39;
            s_in[ly][lx] = bsrc[ly * WIN + lx];
        }
    } else {
        for (int i = tid; i < 38 * 39; i += 256) {
            int ly = i / 39, lx = i - ly * 39;
            int gy = jy0 + ly, gx = jx0 + lx;
            float v = 0.0f;
            if (gy >= 0 && gy < HP && gx >= 0 && gx < WP)
                v = base[refl(gy - MARG) * WIN + refl(gx - MARG)];
            s_in[ly][lx] = v;
        }
    }
    __syncthreads();

    // stage 2: horizontal upsample, row-pairs packed: item = (ly pair, j), 19x33
    for (int i = tid; i < 19 * 33; i += 256) {
        int j = i % 33, lp = i / 33;
        int ly = 2 * lp;
        const float* ra = &s_in[ly][j];
        const float* rb = &s_in[ly + 1][j];
        f2 ev = {0.0f, 0.0f}, od = {0.0f, 0.0f};   // .x = row ly, .y = row ly+1
#pragma unroll
        for (int t = 0; t < 6; ++t) {
            f2 ta; ta.x = ra[t];     ta.y = rb[t];       // ds_read2_b32 (offsets 40 apart)
            f2 tb; tb.x = ra[t + 1]; tb.y = rb[t + 1];
            ev += fs[11 - 2 * t] * ta;
            od += fs[10 - 2 * t] * tb;
        }
        f2 lo; lo.x = ev.x; lo.y = od.x;
        f2 hi; hi.x = ev.y; hi.y = od.y;
        *(f2*)&s_mid[ly][2 * j]     = lo;
        *(f2*)&s_mid[ly + 1][2 * j] = hi;
    }
    __syncthreads();

    // stage 3: vertical upsample, single pass; thread (qx, mg) does row-pairs
    // m = 2mg and 2mg+1 -> rows 2mg..2mg+7 loaded once; outputs gy0..gy0+3.
    // gy0 = ty0 + 4*mg is 0 mod 4 and HU is 0 mod 4 -> whole group in or out.
    {
        int qx = tid & 15;
        int mg = tid >> 4;            // 0..15
        int m0 = 2 * mg;
        int gx0 = tx0 + 4 * qx;
        int gy0 = ty0 + 4 * mg;
        __fp16* upch = ups + (size_t)ch * CHELEMS;
        if (gy0 < HU) {
            if (gx0 + 3 < WU) {
                float4 r0 = *(const float4*)&s_mid[m0 + 0][4 * qx];
                float4 r1 = *(const float4*)&s_mid[m0 + 1][4 * qx];
                float4 r2 = *(const float4*)&s_mid[m0 + 2][4 * qx];
                float4 r3 = *(const float4*)&s_mid[m0 + 3][4 * qx];
                float4 r4 = *(const float4*)&s_mid[m0 + 4][4 * qx];
                float4 r5 = *(const float4*)&s_mid[m0 + 5][4 * qx];
                float4 r6 = *(const float4*)&s_mid[m0 + 6][4 * qx];
                float4 r7 = *(const float4*)&s_mid[m0 + 7][4 * qx];
                f2 a0; a0.x = r0.x; a0.y = r0.y;  f2 b0; b0.x = r0.z; b0.y = r0.w;
                f2 a1; a1.x = r1.x; a1.y = r1.y;  f2 b1; b1.x = r1.z; b1.y = r1.w;
                f2 a2; a2.x = r2.x; a2.y = r2.y;  f2 b2; b2.x = r2.z; b2.y = r2.w;
                f2 a3; a3.x = r3.x; a3.y = r3.y;  f2 b3; b3.x = r3.z; b3.y = r3.w;
                f2 a4; a4.x = r4.x; a4.y = r4.y;  f2 b4; b4.x = r4.z; b4.y = r4.w;
                f2 a5; a5.x = r5.x; a5.y = r5.y;  f2 b5; b5.x = r5.z; b5.y = r5.w;
                f2 a6; a6.x = r6.x; a6.y = r6.y;  f2 b6; b6.x = r6.z; b6.y = r6.w;
                f2 a7; a7.x = r7.x; a7.y = r7.y;  f2 b7; b7.x = r7.z; b7.y = r7.w;
                // m = 2mg: even -> row gy0, odd -> gy0+1
                f2 eA01 = fs[11]*a0 + fs[9]*a1 + fs[7]*a2 + fs[5]*a3 + fs[3]*a4 + fs[1]*a5;
                f2 eA23 = fs[11]*b0 + fs[9]*b1 + fs[7]*b2 + fs[5]*b3 + fs[3]*b4 + fs[1]*b5;
                f2 oA01 = fs[10]*a1 + fs[8]*a2 + fs[6]*a3 + fs[4]*a4 + fs[2]*a5 + fs[0]*a6;
                f2 oA23 = fs[10]*b1 + fs[8]*b2 + fs[6]*b3 + fs[4]*b4 + fs[2]*b5 + fs[0]*b6;
                // m = 2mg+1: even -> row gy0+2, odd -> gy0+3
                f2 eB01 = fs[11]*a1 + fs[9]*a2 + fs[7]*a3 + fs[5]*a4 + fs[3]*a5 + fs[1]*a6;
                f2 eB23 = fs[11]*b1 + fs[9]*b2 + fs[7]*b3 + fs[5]*b4 + fs[3]*b5 + fs[1]*b6;
                f2 oB01 = fs[10]*a2 + fs[8]*a3 + fs[6]*a4 + fs[4]*a5 + fs[2]*a6 + fs[0]*a7;
                f2 oB23 = fs[10]*b2 + fs[8]*b3 + fs[6]*b4 + fs[4]*b5 + fs[2]*b6 + fs[0]*b7;
                uint2 q0, q1, q2, q3;
                q0.x = hbits(eA01.x, eA01.y); q0.y = hbits(eA23.x, eA23.y);
                q1.x = hbits(oA01.x, oA01.y); q1.y = hbits(oA23.x, oA23.y);
                q2.x = hbits(eB01.x, eB01.y); q2.y = hbits(eB23.x, eB23.y);
                q3.x = hbits(oB01.x, oB01.y); q3.y = hbits(oB23.x, oB23.y);
                *(uint2*)&upch[(size_t)(gy0 + 0) * UPITCH + gx0] = q0;
                *(uint2*)&upch[(size_t)(gy0 + 1) * UPITCH + gx0] = q1;
                *(uint2*)&upch[(size_t)(gy0 + 2) * UPITCH + gx0] = q2;
                *(uint2*)&upch[(size_t)(gy0 + 3) * UPITCH + gx0] = q3;
            } else if (gx0 >= WU && gx0 < UPITCH) {
                uint2 z; z.x = 0u; z.y = 0u;   // zero pad cols 664..671
                *(uint2*)&upch[(size_t)(gy0 + 0) * UPITCH + gx0] = z;
                *(uint2*)&upch[(size_t)(gy0 + 1) * UPITCH + gx0] = z;
                *(uint2*)&upch[(size_t)(gy0 + 2) * UPITCH + gx0] = z;
                *(uint2*)&upch[(size_t)(gy0 + 3) * UPITCH + gx0] = z;
            }
        }
    }
}

// ---------------- gather helpers ----------------
// act-free: out-of-tile samples (lwy/lwx in [74,80)) write into s_wh's padding
// (max waddr 79*82+79 = 6557 < 6560), which ph2 never reads (rows<74, cols<=73).
struct GS {
    int a_rd;        // clamped LDS byte addr of (ly, e) halfword pair
    unsigned sh;     // alignbit shift (0 or 16)
    int waddr;       // s_wh element index
    float wyf;       // y lerp weight
    h2 wv;           // packed (1-wx, wx)
};

__device__ __forceinline__ GS gmake(float rx, float ry, int wadd) {
    GS g;
    int lx = (int)rx;                               // trunc == floor (rx>=0 when in-tile)
    int ly = (int)ry;
    float wx = __builtin_amdgcn_fractf(rx);         // == rx - floor(rx); exact, 1 instr
    g.wyf    = __builtin_amdgcn_fractf(ry);
    unsigned a = (unsigned)(ly * PWB + (lx & ~1) * 2);
    const unsigned amax = (PH - 1) * PWB - 8;
    g.a_rd = (int)(a > amax ? amax : a);            // single v_min_u32: negatives wrap huge
    g.sh = ((unsigned)lx & 1u) << 4;
    g.waddr = wadd;
    g.wv = __builtin_amdgcn_cvt_pkrtz(1.0f - wx, wx);
    return g;
}

__device__ __forceinline__ void gfinish(const GS& g, unsigned w0, unsigned w1,
                                        unsigned w2, unsigned w3, __fp16* s_wh) {
    unsigned u0 = __builtin_amdgcn_alignbit(w1, w0, g.sh);
    unsigned u1 = __builtin_amdgcn_alignbit(w3, w2, g.sh);
    h2 h0; *(unsigned*)&h0 = u0;
    h2 h1; *(unsigned*)&h1 = u1;
    float r0 = __builtin_amdgcn_fdot2(h0, g.wv, 0.0f, false);
    float r1 = __builtin_amdgcn_fdot2(h1, g.wv, 0.0f, false);
    s_wh[g.waddr] = (__fp16)(r0 + g.wyf * (r1 - r0));   // unconditional
}

// ---------------- KB: LDS-staged bilinear warp + 2x downsample (512 threads) ----------------
__global__ void __launch_bounds__(512) k_warpdn(const __fp16* __restrict__ ups,
                                                const float* __restrict__ coef,
                                                const float* __restrict__ hz,
                                                float* __restrict__ out,
                                                int n0, int ch0) {
    __shared__ __align__(16) unsigned char s_raw[PH * PWB];      // 40.1 KB
    __shared__ __fp16 s_wh[80 * 82];                             // 13.1 KB
    __fp16* s_src = (__fp16*)s_raw;
    h2*     s_m2  = (h2*)s_raw;      // aliases s_src (disjoint live ranges)

    int ch  = blockIdx.z;
    int ty0 = blockIdx.y * 32;
    int tx0 = blockIdx.x * 32;
    int tid = threadIdx.x;
    const float* cf = coef + (size_t)(n0 + ch / CH) * 6;
    float cxx = cf[0], cxy = cf[1], cx0 = cf[2];
    float cyx = cf[3], cyy = cf[4], cy0 = cf[5];
    const __fp16* upc = ups + (size_t)ch * CHELEMS;
    const unsigned short* us = (const unsigned short*)upc;
    int wy0 = 2 * ty0 + 1, wx0 = 2 * tx0 + 1;
    float wx0f = (float)wx0, wy0f = (float)wy0;

    // source bbox from tile corners (affine -> corners bound everything)
    float ix00 = cxx * wx0f + cxy * wy0f + cx0;
    float iy00 = cyx * wx0f + cyy * wy0f + cy0;
    float dxx = cxx * 73.0f, dxy = cxy * 73.0f;
    float dyx = cyx * 73.0f, dyy = cyy * 73.0f;
    float ixmin = ix00 + fminf(dxx, 0.0f) + fminf(dxy, 0.0f);
    float ixmax = ix00 + fmaxf(dxx, 0.0f) + fmaxf(dxy, 0.0f);
    float iymin = iy00 + fminf(dyx, 0.0f) + fminf(dyy, 0.0f);
    float iymax = iy00 + fmaxf(dyx, 0.0f) + fmaxf(dyy, 0.0f);
    int x_lo = (int)floorf(ixmin) - 1;
    int x_base = x_lo & ~7;
    int x_hi = (int)floorf(ixmax) + 2;
    int y_lo = (int)floorf(iymin) - 1;
    int y_hi = (int)floorf(iymax) + 2;
    int Rn = y_hi - y_lo + 1;
    int Wn = x_hi - x_base + 1;
    bool ldsok = (Rn <= PH) && (Wn <= PW);

    int wave = __builtin_amdgcn_readfirstlane(tid >> 6);   // 0..7
    int lane = tid & 63;
    int ply = lane >> 3, plx = lane & 7;
    float ix_l = cxx * (float)(wx0 + plx) + cxy * (float)(wy0 + ply) + cx0;
    float iy_l = cyx * (float)(wx0 + plx) + cyy * (float)(wy0 + ply) + cy0;
    float c8xx = 8.0f * cxx, c8xy = 8.0f * cxy;
    float c8yx = 8.0f * cyx, c8yy = 8.0f * cyy;

    if (ldsok) {
        // ---- stage bbox into LDS, dense per-lane (row,slot) mapping ----
        int spr = (Wn + 7) >> 3;                  // slots per row, <= 19
        int rpp = 64 / spr;                       // rows per wave-pass
        float rcp = 1.0f / (float)spr;
        int lrow = (int)((float)lane * rcp);
        if (lrow * spr > lane) lrow--;
        if ((lrow + 1) * spr <= lane) lrow++;
        int lslot = lane - lrow * spr;
        // interior: every staged 16B chunk is in-bounds (block-uniform branch)
        bool sint = (y_lo >= 0) && (y_lo + Rn <= HU) &&
                    (x_base >= 0) && (x_base + spr * 8 <= UPITCH);
        if (lrow < rpp) {
            int gx = x_base + lslot * 8;
            if (sint) {
                const unsigned char* src = (const unsigned char*)
                    &upc[(size_t)(y_lo + wave * rpp + lrow) * UPITCH + gx];
                for (int row = wave * rpp + lrow; row < Rn; row += 8 * rpp) {
                    *(uint4*)&s_src[row * PW + lslot * 8] = *(const uint4*)src;
                    src += (size_t)(8 * rpp) * UPITCH * sizeof(__fp16);
                }
            } else {
                for (int row = wave * rpp + lrow; row < Rn; row += 8 * rpp) {
                    int gy = y_lo + row;
                    uint4 val;
                    if (gy >= 0 && gy < HU && gx >= 0 && gx <= UPITCH - 8) {
                        val = *(const uint4*)&upc[(size_t)gy * UPITCH + gx];
                    } else if (gy >= 0 && gy < HU) {
                        unsigned part[4];
#pragma unroll
                        for (int k = 0; k < 4; ++k) {
                            int ga = gx + 2 * k, gb = ga + 1;
                            unsigned lo = (ga >= 0 && ga < WU) ? (unsigned)us[(size_t)gy * UPITCH + ga] : 0u;
                            unsigned hi = (gb >= 0 && gb < WU) ? (unsigned)us[(size_t)gy * UPITCH + gb] : 0u;
                            part[k] = lo | (hi << 16);
                        }
                        val.x = part[0]; val.y = part[1]; val.z = part[2]; val.w = part[3];
                    } else {
                        val.x = 0u; val.y = 0u; val.z = 0u; val.w = 0u;
                    }
                    *(uint4*)&s_src[row * PW + lslot * 8] = val;
                }
            }
        }
        __syncthreads();

        // ---- warp from LDS: depth-2 pipelined, column-major incremental stepping ----
        float ixb = ix_l - (float)x_base;
        float iyb = iy_l - (float)y_lo;
        int wbase = ply * 82 + plx;
        float rx = ixb + (float)wave * c8xy;          // px=0, py=wave
        float ry = iyb + (float)wave * c8yy;
        int wadd = wbase + wave * 656;
        int py = wave;
        const float sxA = 8.0f * c8xy,            syA = 8.0f * c8yy;
        const float sxB = c8xx - 2.0f * c8xy,     syB = c8yx - 2.0f * c8yy;
        int tc = (wave < 4) ? 13 : 12;            // idx = wave + 8k < 100

        GS g0 = gmake(rx, ry, wadd);
        {   int pyn = py + 8;
            if (pyn >= 10) { rx += sxB; ry += syB; wadd += 8 - 2 * 656; py = pyn - 10; }
            else           { rx += sxA; ry += syA; wadd += 8 * 656;     py = pyn; } }
        const unsigned* q0 = (const unsigned*)(s_raw + g0.a_rd);
        unsigned a0 = q0[0], a1 = q0[1], a2 = q0[PWB / 4], a3 = q0[PWB / 4 + 1];
        for (int k = 1; k < tc; ++k) {
            GS g1 = gmake(rx, ry, wadd);
            {   int pyn = py + 8;
                if (pyn >= 10) { rx += sxB; ry += syB; wadd += 8 - 2 * 656; py = pyn - 10; }
                else           { rx += sxA; ry += syA; wadd += 8 * 656;     py = pyn; } }
            const unsigned* q1 = (const unsigned*)(s_raw + g1.a_rd);
            unsigned b0 = q1[0], b1 = q1[1], b2 = q1[PWB / 4], b3 = q1[PWB / 4 + 1];
            gfinish(g0, a0, a1, a2, a3, s_wh);
            g0 = g1; a0 = b0; a1 = b1; a2 = b2; a3 = b3;
        }
        gfinish(g0, a0, a1, a2, a3, s_wh);
    } else {
        // ---- fallback: guarded global gather (rare: bbox too large) ----
        for (int pp = wave; pp < 100; pp += 8) {
            int py = (pp * 205) >> 11;
            int px = pp - py * 10;
            int lwy = py * 8 + ply;
            int lwx = px * 8 + plx;
            if (lwy < 74 && lwx < 74) {
                float ix = ix_l + (float)px * c8xx + (float)py * c8xy;
                float iy = iy_l + (float)px * c8yx + (float)py * c8yy;
                float fx = floorf(ix), fy = floorf(iy);
                float wx = ix - fx, wyf = iy - fy;
                int x0 = (int)fx, y0 = (int)fy;
                int xc0 = min(max(x0, 0), WU - 1);
                int xc1 = min(max(x0 + 1, 0), WU - 1);
                int yc0 = min(max(y0, 0), HU - 1);
                int yc1 = min(max(y0 + 1, 0), HU - 1);
                float mx0 = (x0 >= 0 && x0 < WU) ? 1.0f : 0.0f;
                float mx1 = (x0 >= -1 && x0 < WU - 1) ? 1.0f : 0.0f;
                float my0 = (y0 >= 0 && y0 < HU) ? 1.0f : 0.0f;
                float my1 = (y0 >= -1 && y0 < HU - 1) ? 1.0f : 0.0f;
                float t00 = (float)upc[(size_t)yc0 * UPITCH + xc0] * mx0;
                float t01 = (float)upc[(size_t)yc0 * UPITCH + xc1] * mx1;
                float t10 = (float)upc[(size_t)yc1 * UPITCH + xc0] * mx0;
                float t11 = (float)upc[(size_t)yc1 * UPITCH + xc1] * mx1;
                float r0 = t00 + wx * (t01 - t00);
                float r1 = t10 + wx * (t11 - t10);
                s_wh[lwy * 82 + lwx] = (__fp16)(r0 * (1.0f - wyf) * my0 + r1 * wyf * my1);
            }
        }
    }
    __syncthreads();

    // packed filter registers
    float f[12];
#pragma unroll
    for (int i = 0; i < 12; ++i) f[i] = hz[i];
    h2 Fe[6];
#pragma unroll
    for (int i = 0; i < 6; ++i) { Fe[i][0] = (__fp16)f[2 * i]; Fe[i][1] = (__fp16)f[2 * i + 1]; }

    // phase 2: horizontal downsample via fdot2 on fp16 pairs -> s_m2 (aliases s_src)
    for (int i = tid; i < 74 * 16; i += 512) {
        int j = i & 15, lwy = i >> 4;
        const __fp16* r = &s_wh[lwy * 82 + 4 * j];
        h2 P0 = *(const h2*)(r + 0);
        h2 P1 = *(const h2*)(r + 2);
        h2 P2 = *(const h2*)(r + 4);
        h2 P3 = *(const h2*)(r + 6);
        h2 P4 = *(const h2*)(r + 8);
        h2 P5 = *(const h2*)(r + 10);
        h2 P6 = *(const h2*)(r + 12);
        float ev = __builtin_amdgcn_fdot2(P0, Fe[0],
                   __builtin_amdgcn_fdot2(P1, Fe[1],
                   __builtin_amdgcn_fdot2(P2, Fe[2],
                   __builtin_amdgcn_fdot2(P3, Fe[3],
                   __builtin_amdgcn_fdot2(P4, Fe[4],
                   __builtin_amdgcn_fdot2(P5, Fe[5], 0.0f, false), false), false), false), false), false);
        float od = __builtin_amdgcn_fdot2(P1, Fe[0],
                   __builtin_amdgcn_fdot2(P2, Fe[1],
                   __builtin_amdgcn_fdot2(P3, Fe[2],
                   __builtin_amdgcn_fdot2(P4, Fe[3],
                   __builtin_amdgcn_fdot2(P5, Fe[4],
                   __builtin_amdgcn_fdot2(P6, Fe[5], 0.0f, false), false), false), false), false), false);
        h2 sm; sm[0] = (__fp16)ev; sm[1] = (__fp16)od;
        s_m2[lwy * 17 + j] = sm;
    }
    __syncthreads();

    // phase 3: vertical downsample via perm-paired fdot2
    {
        int j = tid & 15, my = tid >> 4;    // 512 threads == 32x16 exactly
        const unsigned* m2u = (const unsigned*)s_m2;
        float ev = 0.0f, od = 0.0f;
#pragma unroll
        for (int t = 0; t < 12; t += 2) {
            unsigned ha = m2u[(2 * my + t) * 17 + j];
            unsigned hb = m2u[(2 * my + t + 1) * 17 + j];
            unsigned pe = __builtin_amdgcn_perm(hb, ha, 0x05040100u);  // (ha.lo, hb.lo)
            unsigned po = __builtin_amdgcn_perm(hb, ha, 0x07060302u);  // (ha.hi, hb.hi)
            h2 he; *(unsigned*)&he = pe;
            h2 ho; *(unsigned*)&ho = po;
            ev = __builtin_amdgcn_fdot2(he, Fe[t >> 1], ev, false);
            od = __builtin_amdgcn_fdot2(ho, Fe[t >> 1], od, false);
        }
        float2 o; o.x = ev; o.y = od;
        *(float2*)&out[(size_t)(ch0 + ch) * HO * WO + (size_t)(ty0 + my) * WO + (tx0 + 2 * j)] = o;
    }
}

// ---------------- launch ----------------
extern "C" void kernel_launch(void* const* d_in, const int* in_sizes, int n_in,
                              void* d_out, int out_size, void* d_ws, size_t ws_size,
                              hipStream_t stream) {
    const float* images = (const float*)d_in[0];
    const float* theta  = (const float*)d_in[1];
    const float* log_s  = (const float*)d_in[2];
    const float* tx     = (const float*)d_in[3];
    const float* ty     = (const float*)d_in[4];
    const float* hz     = (const float*)d_in[5];
    float* out = (float*)d_out;
    float* ws  = (float*)d_ws;

    // cn=32: single chunk (85.6 MB intermediate). Removes dispatch gaps; warpdn
    // 6144 blocks @ 3/CU = 8 full residency rounds (round-2 lesson: partial
    // rounds = 2x tail loss). k_setup separate (round-11 lesson: inlining
    // transcendentals into 6144 blocks costs +8 us).
    int cn = 32;
    while (cn > 1) {
        size_t needed = 1024 + (size_t)cn * CH * CHELEMS * sizeof(__fp16);
        if (needed <= ws_size) break;
        cn >>= 1;
    }
    float* coef = ws;
    __fp16* upsb = (__fp16*)(ws + 256);

    hipLaunchKernelGGL(k_setup, dim3(1), dim3(32), 0, stream, theta, log_s, tx, ty, coef);

    const int TA = (HU + 63) / 64;    // 11
    for (int n0 = 0; n0 < NIMG; n0 += cn) {
        int nch = cn * CH;
        int ch0 = n0 * CH;
        hipLaunchKernelGGL(k_up2, dim3(TA, TA, nch), dim3(256), 0, stream,
                           images, hz, upsb, ch0);
        hipLaunchKernelGGL(k_warpdn, dim3(WO / 32, HO / 32, nch), dim3(512), 0, stream,
                           upsb, coef, hz, out, n0, ch0);
    }
}

// Round 13
// 93.326 us; speedup vs baseline: 1.0242x; 1.0114x over previous
//
#include <hip/hip_runtime.h>
#include <hip/hip_fp16.h>

// ---------------- problem constants ----------------
#define NIMG 32
#define CH   3
#define HIN  256
#define WIN  256
#define MARG 38          // 2*HZ_PAD + 32
#define HP   332         // HIN + 2*MARG
#define WP   332
#define HU   664         // 2*HP
#define WU   664
#define HO   256
#define WO   256

// plain fp16 upsampled intermediate, padded row pitch (cols 664..671 are zeros)
#define UPITCH  672
#define CHELEMS (664 * 672)

// LDS staging window for the warp (per 32x32 output tile)
#define PH 132            // max rows
#define PW 152            // max cols (19 x 8-elem slots), 8-aligned base
#define PWB (PW * 2)      // row pitch in bytes (304)

typedef __fp16 h2 __attribute__((ext_vector_type(2)));
typedef float  f2 __attribute__((ext_vector_type(2)));

// reflect (edge-excluding) for original 256-range, valid for r in [-255, 510]
__device__ __forceinline__ int refl(int r) {
    r = (r < 0) ? -r : r;
    return (r > 255) ? (510 - r) : r;
}

// ---------------- per-image affine coefficients (ONCE per batch; round-11 lesson:
// inlining this into warpdn repeats transcendentals 6144x = +8 us) ----------------
__global__ void k_setup(const float* __restrict__ th, const float* __restrict__ ls,
                        const float* __restrict__ txp, const float* __restrict__ typ,
                        float* __restrict__ coef) {
    int n = blockIdx.x * blockDim.x + threadIdx.x;
    if (n >= NIMG) return;
    float c  = cosf(th[n]);
    float sn = sinf(th[n]);
    float inv_s = 1.0f / expf(ls[n]);
    float tX = -txp[n] * (float)WIN;
    float tY = -typ[n] * (float)HIN;
    float A00 = inv_s * c,    A01 = inv_s * sn,  A02 = inv_s * (c * tX + sn * tY);
    float A10 = -inv_s * sn,  A11 = inv_s * c,   A12 = inv_s * (-sn * tX + c * tY);
    A02 *= 2.0f; A12 *= 2.0f;
    A02 += 0.5f * (A00 + A01) - 0.5f;
    A12 += 0.5f * (A10 + A11) - 0.5f;
    const float Wu = (float)HU, Hu = (float)HU;
    const float Wt = 524.0f, Ht = 524.0f;
    float B00 = A00 * (2.0f / Wu) * (Wt * 0.5f);
    float B01 = A01 * (2.0f / Wu) * (Ht * 0.5f);
    float B02 = A02 * (2.0f / Wu);
    float B10 = A10 * (2.0f / Hu) * (Wt * 0.5f);
    float B11 = A11 * (2.0f / Hu) * (Ht * 0.5f);
    float B12 = A12 * (2.0f / Hu);
    float cxx = B00 * Wu / Wt;
    float cxy = B01 * Wu / Ht;
    float cx0 = 0.5f * ((B00 * (1.0f / Wt - 1.0f) + B01 * (1.0f / Ht - 1.0f) + B02 + 1.0f) * Wu - 1.0f);
    float cyx = B10 * Hu / Wt;
    float cyy = B11 * Hu / Ht;
    float cy0 = 0.5f * ((B10 * (1.0f / Wt - 1.0f) + B11 * (1.0f / Ht - 1.0f) + B12 + 1.0f) * Hu - 1.0f);
    coef[n * 6 + 0] = cxx;
    coef[n * 6 + 1] = cxy;
    coef[n * 6 + 2] = cx0;
    coef[n * 6 + 3] = cyx;
    coef[n * 6 + 4] = cyy;
    coef[n * 6 + 5] = cy0;
}

__device__ __forceinline__ unsigned hbits(float a, float b) {
    __half2 h = __floats2half2_rn(a, b);
    return *(unsigned*)&h;
}

// ---------------- KA: fused reflect-pad + 2x upsample -> plain fp16 (padded pitch) ----------------
// (identical to round-12: interior stage-1 fast path; packed stage-2; single-pass
// stage-3 with adjacent-row-pair reuse)
__global__ void __launch_bounds__(256) k_up2(const float* __restrict__ img,
                                             const float* __restrict__ hz,
                                             __fp16* __restrict__ ups, int ch0) {
    __shared__ float s_in[38][40];    // 38 rows x 39 cols used
    __shared__ float s_mid[38][68];   // cols 0..65 used
    int ch  = blockIdx.z;
    int ty0 = blockIdx.y * 64;
    int tx0 = blockIdx.x * 64;
    int jy0 = (ty0 >> 1) - 3;
    int jx0 = (tx0 >> 1) - 3;
    int tid = threadIdx.x;
    float fs[12];                     // 2*f[i] (exact scaling)
#pragma unroll
    for (int i = 0; i < 12; ++i) fs[i] = 2.0f * hz[i];
    const float* base = img + (size_t)(ch0 + ch) * HIN * WIN;

    // stage 1: padded input patch (38 x 39), zero outside [0,332)^2
    if (jy0 >= 38 && jy0 <= 256 && jx0 >= 38 && jx0 <= 255) {
        const float* bsrc = base + (jy0 - MARG) * WIN + (jx0 - MARG);
        for (int i = tid; i < 38 * 39; i += 256) {
            int ly = i / 39, lx = i - ly * 39;
            s_in[ly][lx] = bsrc[ly * WIN + lx];
        }
    } else {
        for (int i = tid; i < 38 * 39; i += 256) {
            int ly = i / 39, lx = i - ly * 39;
            int gy = jy0 + ly, gx = jx0 + lx;
            float v = 0.0f;
            if (gy >= 0 && gy < HP && gx >= 0 && gx < WP)
                v = base[refl(gy - MARG) * WIN + refl(gx - MARG)];
            s_in[ly][lx] = v;
        }
    }
    __syncthreads();

    // stage 2: horizontal upsample, row-pairs packed: item = (ly pair, j), 19x33
    for (int i = tid; i < 19 * 33; i += 256) {
        int j = i % 33, lp = i / 33;
        int ly = 2 * lp;
        const float* ra = &s_in[ly][j];
        const float* rb = &s_in[ly + 1][j];
        f2 ev = {0.0f, 0.0f}, od = {0.0f, 0.0f};   // .x = row ly, .y = row ly+1
#pragma unroll
        for (int t = 0; t < 6; ++t) {
            f2 ta; ta.x = ra[t];     ta.y = rb[t];       // ds_read2_b32 (offsets 40 apart)
            f2 tb; tb.x = ra[t + 1]; tb.y = rb[t + 1];
            ev += fs[11 - 2 * t] * ta;
            od += fs[10 - 2 * t] * tb;
        }
        f2 lo; lo.x = ev.x; lo.y = od.x;
        f2 hi; hi.x = ev.y; hi.y = od.y;
        *(f2*)&s_mid[ly][2 * j]     = lo;
        *(f2*)&s_mid[ly + 1][2 * j] = hi;
    }
    __syncthreads();

    // stage 3: vertical upsample, single pass; thread (qx, mg) does row-pairs
    // m = 2mg and 2mg+1 -> rows 2mg..2mg+7 loaded once; outputs gy0..gy0+3.
    {
        int qx = tid & 15;
        int mg = tid >> 4;            // 0..15
        int m0 = 2 * mg;
        int gx0 = tx0 + 4 * qx;
        int gy0 = ty0 + 4 * mg;
        __fp16* upch = ups + (size_t)ch * CHELEMS;
        if (gy0 < HU) {
            if (gx0 + 3 < WU) {
                float4 r0 = *(const float4*)&s_mid[m0 + 0][4 * qx];
                float4 r1 = *(const float4*)&s_mid[m0 + 1][4 * qx];
                float4 r2 = *(const float4*)&s_mid[m0 + 2][4 * qx];
                float4 r3 = *(const float4*)&s_mid[m0 + 3][4 * qx];
                float4 r4 = *(const float4*)&s_mid[m0 + 4][4 * qx];
                float4 r5 = *(const float4*)&s_mid[m0 + 5][4 * qx];
                float4 r6 = *(const float4*)&s_mid[m0 + 6][4 * qx];
                float4 r7 = *(const float4*)&s_mid[m0 + 7][4 * qx];
                f2 a0; a0.x = r0.x; a0.y = r0.y;  f2 b0; b0.x = r0.z; b0.y = r0.w;
                f2 a1; a1.x = r1.x; a1.y = r1.y;  f2 b1; b1.x = r1.z; b1.y = r1.w;
                f2 a2; a2.x = r2.x; a2.y = r2.y;  f2 b2; b2.x = r2.z; b2.y = r2.w;
                f2 a3; a3.x = r3.x; a3.y = r3.y;  f2 b3; b3.x = r3.z; b3.y = r3.w;
                f2 a4; a4.x = r4.x; a4.y = r4.y;  f2 b4; b4.x = r4.z; b4.y = r4.w;
                f2 a5; a5.x = r5.x; a5.y = r5.y;  f2 b5; b5.x = r5.z; b5.y = r5.w;
                f2 a6; a6.x = r6.x; a6.y = r6.y;  f2 b6; b6.x = r6.z; b6.y = r6.w;
                f2 a7; a7.x = r7.x; a7.y = r7.y;  f2 b7; b7.x = r7.z; b7.y = r7.w;
                f2 eA01 = fs[11]*a0 + fs[9]*a1 + fs[7]*a2 + fs[5]*a3 + fs[3]*a4 + fs[1]*a5;
                f2 eA23 = fs[11]*b0 + fs[9]*b1 + fs[7]*b2 + fs[5]*b3 + fs[3]*b4 + fs[1]*b5;
                f2 oA01 = fs[10]*a1 + fs[8]*a2 + fs[6]*a3 + fs[4]*a4 + fs[2]*a5 + fs[0]*a6;
                f2 oA23 = fs[10]*b1 + fs[8]*b2 + fs[6]*b3 + fs[4]*b4 + fs[2]*b5 + fs[0]*b6;
                f2 eB01 = fs[11]*a1 + fs[9]*a2 + fs[7]*a3 + fs[5]*a4 + fs[3]*a5 + fs[1]*a6;
                f2 eB23 = fs[11]*b1 + fs[9]*b2 + fs[7]*b3 + fs[5]*b4 + fs[3]*b5 + fs[1]*b6;
                f2 oB01 = fs[10]*a2 + fs[8]*a3 + fs[6]*a4 + fs[4]*a5 + fs[2]*a6 + fs[0]*a7;
                f2 oB23 = fs[10]*b2 + fs[8]*b3 + fs[6]*b4 + fs[4]*b5 + fs[2]*b6 + fs[0]*b7;
                uint2 q0, q1, q2, q3;
                q0.x = hbits(eA01.x, eA01.y); q0.y = hbits(eA23.x, eA23.y);
                q1.x = hbits(oA01.x, oA01.y); q1.y = hbits(oA23.x, oA23.y);
                q2.x = hbits(eB01.x, eB01.y); q2.y = hbits(eB23.x, eB23.y);
                q3.x = hbits(oB01.x, oB01.y); q3.y = hbits(oB23.x, oB23.y);
                *(uint2*)&upch[(size_t)(gy0 + 0) * UPITCH + gx0] = q0;
                *(uint2*)&upch[(size_t)(gy0 + 1) * UPITCH + gx0] = q1;
                *(uint2*)&upch[(size_t)(gy0 + 2) * UPITCH + gx0] = q2;
                *(uint2*)&upch[(size_t)(gy0 + 3) * UPITCH + gx0] = q3;
            } else if (gx0 >= WU && gx0 < UPITCH) {
                uint2 z; z.x = 0u; z.y = 0u;   // zero pad cols 664..671
                *(uint2*)&upch[(size_t)(gy0 + 0) * UPITCH + gx0] = z;
                *(uint2*)&upch[(size_t)(gy0 + 1) * UPITCH + gx0] = z;
                *(uint2*)&upch[(size_t)(gy0 + 2) * UPITCH + gx0] = z;
                *(uint2*)&upch[(size_t)(gy0 + 3) * UPITCH + gx0] = z;
            }
        }
    }
}

// ---------------- gather helpers ----------------
// act-free: out-of-tile samples (lwy in [74,76), lwx in [74,80)) write into s_wh's
// padding (max waddr 75*82+79 = 6229 < 6560), which ph2 never reads (rows<74, cols<=73).
struct GS {
    int a_rd;        // clamped LDS byte addr of (ly, e) halfword pair
    unsigned sh;     // alignbit shift (0 or 16)
    int waddr;       // s_wh element index
    float wyf;       // y lerp weight
    h2 wv;           // packed (1-wx, wx)
};

__device__ __forceinline__ GS gmake(float rx, float ry, int wadd) {
    GS g;
    int lx = (int)rx;                               // trunc == floor (rx>=0 when in-tile)
    int ly = (int)ry;
    float wx = __builtin_amdgcn_fractf(rx);         // == rx - floor(rx); exact, 1 instr
    g.wyf    = __builtin_amdgcn_fractf(ry);
    unsigned a = (unsigned)(ly * PWB + (lx & ~1) * 2);
    const unsigned amax = (PH - 1) * PWB - 8;
    g.a_rd = (int)(a > amax ? amax : a);            // single v_min_u32: negatives wrap huge
    g.sh = ((unsigned)lx & 1u) << 4;
    g.waddr = wadd;
    g.wv = __builtin_amdgcn_cvt_pkrtz(1.0f - wx, wx);
    return g;
}

__device__ __forceinline__ void gfinish(const GS& g, unsigned w0, unsigned w1,
                                        unsigned w2, unsigned w3, __fp16* s_wh) {
    unsigned u0 = __builtin_amdgcn_alignbit(w1, w0, g.sh);
    unsigned u1 = __builtin_amdgcn_alignbit(w3, w2, g.sh);
    h2 h0; *(unsigned*)&h0 = u0;
    h2 h1; *(unsigned*)&h1 = u1;
    float r0 = __builtin_amdgcn_fdot2(h0, g.wv, 0.0f, false);
    float r1 = __builtin_amdgcn_fdot2(h1, g.wv, 0.0f, false);
    s_wh[g.waddr] = (__fp16)(r0 + g.wyf * (r1 - r0));   // unconditional
}

// ---------------- KB: LDS-staged bilinear warp + 2x downsample (512 threads) ----------------
// Gather: 4x16 subtiles -> 19x5 = 95 subtiles (was 10x10=100): lane waste 14.4%->2.8% of
// grid, max slots/wave 13->12. ph2: paired outputs (j,j+1) -> 592 items (was 1184),
// 9 h2 reads per 2 outputs (was 14).
__global__ void __launch_bounds__(512) k_warpdn(const __fp16* __restrict__ ups,
                                                const float* __restrict__ coef,
                                                const float* __restrict__ hz,
                                                float* __restrict__ out,
                                                int n0, int ch0) {
    __shared__ __align__(16) unsigned char s_raw[PH * PWB];      // 40.1 KB
    __shared__ __fp16 s_wh[80 * 82];                             // 13.1 KB
    __fp16* s_src = (__fp16*)s_raw;
    h2*     s_m2  = (h2*)s_raw;      // aliases s_src (disjoint live ranges)

    int ch  = blockIdx.z;
    int ty0 = blockIdx.y * 32;
    int tx0 = blockIdx.x * 32;
    int tid = threadIdx.x;
    const float* cf = coef + (size_t)(n0 + ch / CH) * 6;
    float cxx = cf[0], cxy = cf[1], cx0 = cf[2];
    float cyx = cf[3], cyy = cf[4], cy0 = cf[5];
    const __fp16* upc = ups + (size_t)ch * CHELEMS;
    const unsigned short* us = (const unsigned short*)upc;
    int wy0 = 2 * ty0 + 1, wx0 = 2 * tx0 + 1;
    float wx0f = (float)wx0, wy0f = (float)wy0;

    // source bbox from tile corners (affine -> corners bound everything)
    float ix00 = cxx * wx0f + cxy * wy0f + cx0;
    float iy00 = cyx * wx0f + cyy * wy0f + cy0;
    float dxx = cxx * 73.0f, dxy = cxy * 73.0f;
    float dyx = cyx * 73.0f, dyy = cyy * 73.0f;
    float ixmin = ix00 + fminf(dxx, 0.0f) + fminf(dxy, 0.0f);
    float ixmax = ix00 + fmaxf(dxx, 0.0f) + fmaxf(dxy, 0.0f);
    float iymin = iy00 + fminf(dyx, 0.0f) + fminf(dyy, 0.0f);
    float iymax = iy00 + fmaxf(dyx, 0.0f) + fmaxf(dyy, 0.0f);
    int x_lo = (int)floorf(ixmin) - 1;
    int x_base = x_lo & ~7;
    int x_hi = (int)floorf(ixmax) + 2;
    int y_lo = (int)floorf(iymin) - 1;
    int y_hi = (int)floorf(iymax) + 2;
    int Rn = y_hi - y_lo + 1;
    int Wn = x_hi - x_base + 1;
    bool ldsok = (Rn <= PH) && (Wn <= PW);

    int wave = __builtin_amdgcn_readfirstlane(tid >> 6);   // 0..7
    int lane = tid & 63;

    if (ldsok) {
        // ---- stage bbox into LDS, dense per-lane (row,slot) mapping ----
        int spr = (Wn + 7) >> 3;                  // slots per row, <= 19
        int rpp = 64 / spr;                       // rows per wave-pass
        float rcp = 1.0f / (float)spr;
        int lrow = (int)((float)lane * rcp);
        if (lrow * spr > lane) lrow--;
        if ((lrow + 1) * spr <= lane) lrow++;
        int lslot = lane - lrow * spr;
        // interior: every staged 16B chunk is in-bounds (block-uniform branch)
        bool sint = (y_lo >= 0) && (y_lo + Rn <= HU) &&
                    (x_base >= 0) && (x_base + spr * 8 <= UPITCH);
        if (lrow < rpp) {
            int gx = x_base + lslot * 8;
            if (sint) {
                const unsigned char* src = (const unsigned char*)
                    &upc[(size_t)(y_lo + wave * rpp + lrow) * UPITCH + gx];
                for (int row = wave * rpp + lrow; row < Rn; row += 8 * rpp) {
                    *(uint4*)&s_src[row * PW + lslot * 8] = *(const uint4*)src;
                    src += (size_t)(8 * rpp) * UPITCH * sizeof(__fp16);
                }
            } else {
                for (int row = wave * rpp + lrow; row < Rn; row += 8 * rpp) {
                    int gy = y_lo + row;
                    uint4 val;
                    if (gy >= 0 && gy < HU && gx >= 0 && gx <= UPITCH - 8) {
                        val = *(const uint4*)&upc[(size_t)gy * UPITCH + gx];
                    } else if (gy >= 0 && gy < HU) {
                        unsigned part[4];
#pragma unroll
                        for (int k = 0; k < 4; ++k) {
                            int ga = gx + 2 * k, gb = ga + 1;
                            unsigned lo = (ga >= 0 && ga < WU) ? (unsigned)us[(size_t)gy * UPITCH + ga] : 0u;
                            unsigned hi = (gb >= 0 && gb < WU) ? (unsigned)us[(size_t)gy * UPITCH + gb] : 0u;
                            part[k] = lo | (hi << 16);
                        }
                        val.x = part[0]; val.y = part[1]; val.z = part[2]; val.w = part[3];
                    } else {
                        val.x = 0u; val.y = 0u; val.z = 0u; val.w = 0u;
                    }
                    *(uint4*)&s_src[row * PW + lslot * 8] = val;
                }
            }
        }
        __syncthreads();

        // ---- warp from LDS: depth-2 pipelined; 4x16 subtiles, 19x5 grid,
        //      column-major wave-uniform incremental stepping ----
        int ply = lane >> 4, plx = lane & 15;     // 4 rows x 16 cols per subtile
        float ix_l = cxx * (float)(wx0 + plx) + cxy * (float)(wy0 + ply) + cx0;
        float iy_l = cyx * (float)(wx0 + plx) + cyy * (float)(wy0 + ply) + cy0;
        float ixb = ix_l - (float)x_base;
        float iyb = iy_l - (float)y_lo;
        float c4xy = 4.0f * cxy, c4yy = 4.0f * cyy;
        int wbase = ply * 82 + plx;
        // idx = wave + 8k decoded column-major on 19 rows: px = idx/19, py = idx%19
        float rx = ixb + (float)wave * c4xy;          // px=0, py=wave
        float ry = iyb + (float)wave * c4yy;
        int wadd = wbase + wave * 328;                // 4*82 per py unit
        int py = wave;
        // stepA (py+=8):  dlwy=+32           -> rx += 32*cxy
        // stepB (wrap: py-=11, px+=1): dlwy=-44, dlwx=+16 -> rx += 16*cxx - 44*cxy
        const float sxA = 32.0f * cxy,                  syA = 32.0f * cyy;
        const float sxB = 16.0f * cxx - 44.0f * cxy,    syB = 16.0f * cyx - 44.0f * cyy;
        int tc = (wave < 7) ? 12 : 11;            // idx = wave + 8k < 95

        GS g0 = gmake(rx, ry, wadd);
        {   int pyn = py + 8;
            if (pyn >= 19) { rx += sxB; ry += syB; wadd += 16 - 44 * 82; py = pyn - 19; }
            else           { rx += sxA; ry += syA; wadd += 32 * 82;      py = pyn; } }
        const unsigned* q0 = (const unsigned*)(s_raw + g0.a_rd);
        unsigned a0 = q0[0], a1 = q0[1], a2 = q0[PWB / 4], a3 = q0[PWB / 4 + 1];
        for (int k = 1; k < tc; ++k) {
            GS g1 = gmake(rx, ry, wadd);
            {   int pyn = py + 8;
                if (pyn >= 19) { rx += sxB; ry += syB; wadd += 16 - 44 * 82; py = pyn - 19; }
                else           { rx += sxA; ry += syA; wadd += 32 * 82;      py = pyn; } }
            const unsigned* q1 = (const unsigned*)(s_raw + g1.a_rd);
            unsigned b0 = q1[0], b1 = q1[1], b2 = q1[PWB / 4], b3 = q1[PWB / 4 + 1];
            gfinish(g0, a0, a1, a2, a3, s_wh);
            g0 = g1; a0 = b0; a1 = b1; a2 = b2; a3 = b3;
        }
        gfinish(g0, a0, a1, a2, a3, s_wh);
    } else {
        // ---- fallback: guarded global gather (rare: bbox too large) ----
        int ply = lane >> 3, plx = lane & 7;
        float ix_l = cxx * (float)(wx0 + plx) + cxy * (float)(wy0 + ply) + cx0;
        float iy_l = cyx * (float)(wx0 + plx) + cyy * (float)(wy0 + ply) + cy0;
        float c8xx = 8.0f * cxx, c8xy = 8.0f * cxy;
        float c8yx = 8.0f * cyx, c8yy = 8.0f * cyy;
        for (int pp = wave; pp < 100; pp += 8) {
            int py = (pp * 205) >> 11;
            int px = pp - py * 10;
            int lwy = py * 8 + ply;
            int lwx = px * 8 + plx;
            if (lwy < 74 && lwx < 74) {
                float ix = ix_l + (float)px * c8xx + (float)py * c8xy;
                float iy = iy_l + (float)px * c8yx + (float)py * c8yy;
                float fx = floorf(ix), fy = floorf(iy);
                float wx = ix - fx, wyf = iy - fy;
                int x0 = (int)fx, y0 = (int)fy;
                int xc0 = min(max(x0, 0), WU - 1);
                int xc1 = min(max(x0 + 1, 0), WU - 1);
                int yc0 = min(max(y0, 0), HU - 1);
                int yc1 = min(max(y0 + 1, 0), HU - 1);
                float mx0 = (x0 >= 0 && x0 < WU) ? 1.0f : 0.0f;
                float mx1 = (x0 >= -1 && x0 < WU - 1) ? 1.0f : 0.0f;
                float my0 = (y0 >= 0 && y0 < HU) ? 1.0f : 0.0f;
                float my1 = (y0 >= -1 && y0 < HU - 1) ? 1.0f : 0.0f;
                float t00 = (float)upc[(size_t)yc0 * UPITCH + xc0] * mx0;
                float t01 = (float)upc[(size_t)yc0 * UPITCH + xc1] * mx1;
                float t10 = (float)upc[(size_t)yc1 * UPITCH + xc0] * mx0;
                float t11 = (float)upc[(size_t)yc1 * UPITCH + xc1] * mx1;
                float r0 = t00 + wx * (t01 - t00);
                float r1 = t10 + wx * (t11 - t10);
                s_wh[lwy * 82 + lwx] = (__fp16)(r0 * (1.0f - wyf) * my0 + r1 * wyf * my1);
            }
        }
    }
    __syncthreads();

    // packed filter registers
    float f[12];
#pragma unroll
    for (int i = 0; i < 12; ++i) f[i] = hz[i];
    h2 Fe[6];
#pragma unroll
    for (int i = 0; i < 6; ++i) { Fe[i][0] = (__fp16)f[2 * i]; Fe[i][1] = (__fp16)f[2 * i + 1]; }

    // phase 2: horizontal downsample, paired outputs (j=2jp, j+1): 592 items,
    // 9 h2 reads per item (cols 8jp..8jp+17, max 73), same 24 fdot2 -> s_m2
    for (int i = tid; i < 74 * 8; i += 512) {
        int jp = i & 7, lwy = i >> 3;
        const __fp16* r = &s_wh[lwy * 82 + 8 * jp];
        h2 P[9];
#pragma unroll
        for (int t = 0; t < 9; ++t) P[t] = *(const h2*)(r + 2 * t);
        float ev0 = __builtin_amdgcn_fdot2(P[0], Fe[0],
                    __builtin_amdgcn_fdot2(P[1], Fe[1],
                    __builtin_amdgcn_fdot2(P[2], Fe[2],
                    __builtin_amdgcn_fdot2(P[3], Fe[3],
                    __builtin_amdgcn_fdot2(P[4], Fe[4],
                    __builtin_amdgcn_fdot2(P[5], Fe[5], 0.0f, false), false), false), false), false), false);
        float od0 = __builtin_amdgcn_fdot2(P[1], Fe[0],
                    __builtin_amdgcn_fdot2(P[2], Fe[1],
                    __builtin_amdgcn_fdot2(P[3], Fe[2],
                    __builtin_amdgcn_fdot2(P[4], Fe[3],
                    __builtin_amdgcn_fdot2(P[5], Fe[4],
                    __builtin_amdgcn_fdot2(P[6], Fe[5], 0.0f, false), false), false), false), false), false);
        float ev1 = __builtin_amdgcn_fdot2(P[2], Fe[0],
                    __builtin_amdgcn_fdot2(P[3], Fe[1],
                    __builtin_amdgcn_fdot2(P[4], Fe[2],
                    __builtin_amdgcn_fdot2(P[5], Fe[3],
                    __builtin_amdgcn_fdot2(P[6], Fe[4],
                    __builtin_amdgcn_fdot2(P[7], Fe[5], 0.0f, false), false), false), false), false), false);
        float od1 = __builtin_amdgcn_fdot2(P[3], Fe[0],
                    __builtin_amdgcn_fdot2(P[4], Fe[1],
                    __builtin_amdgcn_fdot2(P[5], Fe[2],
                    __builtin_amdgcn_fdot2(P[6], Fe[3],
                    __builtin_amdgcn_fdot2(P[7], Fe[4],
                    __builtin_amdgcn_fdot2(P[8], Fe[5], 0.0f, false), false), false), false), false), false);
        h2 s0; s0[0] = (__fp16)ev0; s0[1] = (__fp16)od0;
        h2 s1; s1[0] = (__fp16)ev1; s1[1] = (__fp16)od1;
        s_m2[lwy * 17 + 2 * jp]     = s0;
        s_m2[lwy * 17 + 2 * jp + 1] = s1;
    }
    __syncthreads();

    // phase 3: vertical downsample via perm-paired fdot2
    {
        int j = tid & 15, my = tid >> 4;    // 512 threads == 32x16 exactly
        const unsigned* m2u = (const unsigned*)s_m2;
        float ev = 0.0f, od = 0.0f;
#pragma unroll
        for (int t = 0; t < 12; t += 2) {
            unsigned ha = m2u[(2 * my + t) * 17 + j];
            unsigned hb = m2u[(2 * my + t + 1) * 17 + j];
            unsigned pe = __builtin_amdgcn_perm(hb, ha, 0x05040100u);  // (ha.lo, hb.lo)
            unsigned po = __builtin_amdgcn_perm(hb, ha, 0x07060302u);  // (ha.hi, hb.hi)
            h2 he; *(unsigned*)&he = pe;
            h2 ho; *(unsigned*)&ho = po;
            ev = __builtin_amdgcn_fdot2(he, Fe[t >> 1], ev, false);
            od = __builtin_amdgcn_fdot2(ho, Fe[t >> 1], od, false);
        }
        float2 o; o.x = ev; o.y = od;
        *(float2*)&out[(size_t)(ch0 + ch) * HO * WO + (size_t)(ty0 + my) * WO + (tx0 + 2 * j)] = o;
    }
}

// ---------------- launch ----------------
extern "C" void kernel_launch(void* const* d_in, const int* in_sizes, int n_in,
                              void* d_out, int out_size, void* d_ws, size_t ws_size,
                              hipStream_t stream) {
    const float* images = (const float*)d_in[0];
    const float* theta  = (const float*)d_in[1];
    const float* log_s  = (const float*)d_in[2];
    const float* tx     = (const float*)d_in[3];
    const float* ty     = (const float*)d_in[4];
    const float* hz     = (const float*)d_in[5];
    float* out = (float*)d_out;
    float* ws  = (float*)d_ws;

    // cn=32: single chunk (85.6 MB intermediate). warpdn 6144 blocks @ 3/CU =
    // 8 full residency rounds. k_setup separate (round-11 lesson).
    int cn = 32;
    while (cn > 1) {
        size_t needed = 1024 + (size_t)cn * CH * CHELEMS * sizeof(__fp16);
        if (needed <= ws_size) break;
        cn >>= 1;
    }
    float* coef = ws;
    __fp16* upsb = (__fp16*)(ws + 256);

    hipLaunchKernelGGL(k_setup, dim3(1), dim3(32), 0, stream, theta, log_s, tx, ty, coef);

    const int TA = (HU + 63) / 64;    // 11
    for (int n0 = 0; n0 < NIMG; n0 += cn) {
        int nch = cn * CH;
        int ch0 = n0 * CH;
        hipLaunchKernelGGL(k_up2, dim3(TA, TA, nch), dim3(256), 0, stream,
                           images, hz, upsb, ch0);
        hipLaunchKernelGGL(k_warpdn, dim3(WO / 32, HO / 32, nch), dim3(512), 0, stream,
                           upsb, coef, hz, out, n0, ch0);
    }
}